// Round 1
// baseline (561.695 us; speedup 1.0000x reference)
//
#include <hip/hip_runtime.h>

// LoRA linear: out = x @ (B@A)^T  ==  ((x @ A^T) @ B^T), rank r=16.
// x: [M=8192, 4096] fp32, A: [16, 4096] fp32, B: [4096, 16] fp32.
// Memory-bound: 128 MiB read (x) + 128 MiB write (out) -> ~42 us floor @ 6.3 TB/s.

#define INCH   4096
#define OUTCH  4096
#define RDIM   16
#define MT     16      // rows per block; grid = M/MT = 512 blocks (2 per CU)

__global__ __launch_bounds__(256, 2)
void lora_fused_kernel(const float* __restrict__ X,
                       const float* __restrict__ A,
                       const float* __restrict__ Bm,
                       float* __restrict__ OUT) {
    __shared__ float t_lds[MT][RDIM];   // 1 KiB

    const int tid = threadIdx.x;
    const int m0  = blockIdx.x * MT;

    // ---------------- phase 1: t[row][r] = x[m0+row][:] . A[r][:] ----------------
    // thread (row = tid>>4, r = tid&15) owns one full dot product.
    // x-load: 16 lanes broadcast same addr (4 distinct rows per wave-instr) -> HBM once.
    {
        const int row = tid >> 4;   // 0..15
        const int rr  = tid & 15;   // 0..15
        const float4* __restrict__ xp =
            reinterpret_cast<const float4*>(X + (size_t)(m0 + row) * INCH);
        const float4* __restrict__ ap =
            reinterpret_cast<const float4*>(A + (size_t)rr * INCH);

        float a0 = 0.f, a1 = 0.f, a2 = 0.f, a3 = 0.f;
        #pragma unroll 2
        for (int i = 0; i < INCH / 4; i += 4) {
            float4 x0 = xp[i + 0], x1 = xp[i + 1], x2 = xp[i + 2], x3 = xp[i + 3];
            float4 v0 = ap[i + 0], v1 = ap[i + 1], v2 = ap[i + 2], v3 = ap[i + 3];
            a0 += x0.x * v0.x + x0.y * v0.y + x0.z * v0.z + x0.w * v0.w;
            a1 += x1.x * v1.x + x1.y * v1.y + x1.z * v1.z + x1.w * v1.w;
            a2 += x2.x * v2.x + x2.y * v2.y + x2.z * v2.z + x2.w * v2.w;
            a3 += x3.x * v3.x + x3.y * v3.y + x3.z * v3.z + x3.w * v3.w;
        }
        t_lds[row][rr] = a0 + a1 + a2 + a3;
    }
    __syncthreads();

    // ---------------- phase 2: out[row][o] = sum_r t[row][r] * B[o][r] ----------------
    // wave w -> rows 4w..4w+3; lane covers 4 contiguous o per chunk (coalesced stores).
    {
        const int w    = tid >> 6;   // wave id 0..3
        const int lane = tid & 63;

        // preload this wave's 4 t-rows (uniform LDS broadcast reads)
        float4 t4[4][4];
        #pragma unroll
        for (int q = 0; q < 4; ++q) {
            #pragma unroll
            for (int rq = 0; rq < 4; ++rq) {
                t4[q][rq] = *reinterpret_cast<const float4*>(&t_lds[4 * w + q][4 * rq]);
            }
        }

        for (int c = 0; c < OUTCH / 256; ++c) {
            const int o = c * 256 + lane * 4;
            // B rows for the lane's 4 o values: 256 B contiguous per lane
            const float4* __restrict__ bp =
                reinterpret_cast<const float4*>(Bm + (size_t)o * RDIM);
            float4 bv[4][4];   // [oj][rq]
            #pragma unroll
            for (int oj = 0; oj < 4; ++oj) {
                #pragma unroll
                for (int rq = 0; rq < 4; ++rq) {
                    bv[oj][rq] = bp[oj * 4 + rq];
                }
            }
            #pragma unroll
            for (int q = 0; q < 4; ++q) {
                float o0 = 0.f, o1 = 0.f, o2 = 0.f, o3 = 0.f;
                #pragma unroll
                for (int rq = 0; rq < 4; ++rq) {
                    const float4 tq = t4[q][rq];
                    o0 += tq.x * bv[0][rq].x + tq.y * bv[0][rq].y
                        + tq.z * bv[0][rq].z + tq.w * bv[0][rq].w;
                    o1 += tq.x * bv[1][rq].x + tq.y * bv[1][rq].y
                        + tq.z * bv[1][rq].z + tq.w * bv[1][rq].w;
                    o2 += tq.x * bv[2][rq].x + tq.y * bv[2][rq].y
                        + tq.z * bv[2][rq].z + tq.w * bv[2][rq].w;
                    o3 += tq.x * bv[3][rq].x + tq.y * bv[3][rq].y
                        + tq.z * bv[3][rq].z + tq.w * bv[3][rq].w;
                }
                float4 res = make_float4(o0, o1, o2, o3);
                *reinterpret_cast<float4*>(
                    OUT + (size_t)(m0 + 4 * w + q) * OUTCH + o) = res;
            }
        }
    }
}

extern "C" void kernel_launch(void* const* d_in, const int* in_sizes, int n_in,
                              void* d_out, int out_size, void* d_ws, size_t ws_size,
                              hipStream_t stream) {
    const float* X  = (const float*)d_in[0];   // [M, 4096]
    const float* A  = (const float*)d_in[1];   // [16, 4096]
    const float* Bm = (const float*)d_in[2];   // [4096, 16]
    float*       O  = (float*)d_out;           // [M, 4096]

    const int M = in_sizes[0] / INCH;          // 8192
    dim3 grid(M / MT), block(256);
    hipLaunchKernelGGL(lora_fused_kernel, grid, block, 0, stream, X, A, Bm, O);
}

// Round 3
// 387.763 us; speedup vs baseline: 1.4486x; 1.4486x over previous
//
#include <hip/hip_runtime.h>

// LoRA linear, rank 16:  out = x @ (B@A)^T  ==  (x @ A^T) @ B^T
// x:[M=8192,4096] f32, A:[16,4096] f32, B:[4096,16] f32, out:[M,4096] f32.
// Mandatory traffic: read x 134 MB + write out 134 MB -> ~42 us floor @ 6.3 TB/s.
// Two streaming kernels via d_ws (T partials, 1 MB):
//   k1: T[kb][m][r] = sum_{cols of half kb} x[m][c]*A[r][c]
//   k2: out[m][o]   = sum_r (T[0][m][r]+T[1][m][r]) * B[o][r]

#define INCH  4096
#define OUTCH 4096
#define RD    16

// ---------------------------------------------------------------- kernel 1
// grid = (M/16)*2 blocks of 256 threads. Block = 16 rows x 2048 cols (K-half).
// Wave = 4 rows; lane covers cols (chunk*256 + lane*4): coalesced float4.
// Each A float4 load (L2-resident) feeds 4 rows; each x float4 feeds 16 r's.
__global__ __launch_bounds__(256, 3)
void lora_xa_kernel(const float* __restrict__ X, const float* __restrict__ A,
                    float* __restrict__ Tp, int M) {
    __shared__ float scratch[4][64][20];   // per-wave transpose pad: 20.5 KB

    const int tid  = threadIdx.x;
    const int w    = tid >> 6;
    const int lane = tid & 63;
    const int kb   = blockIdx.x & 1;       // K half
    const int rg   = blockIdx.x >> 1;      // row group
    const int row0 = rg * 16 + w * 4;

    const float4* A4 = reinterpret_cast<const float4*>(A);

    float acc[4][RD];
#pragma unroll
    for (int q = 0; q < 4; ++q)
#pragma unroll
        for (int r = 0; r < RD; ++r) acc[q][r] = 0.f;

    const float4* xp[4];
#pragma unroll
    for (int q = 0; q < 4; ++q)
        xp[q] = reinterpret_cast<const float4*>(
                    X + (size_t)(row0 + q) * INCH + kb * 2048) + lane;

    // 2-deep x prefetch: next chunk's loads issue before current chunk's FMAs.
    float4 xc[4], xn[4];
#pragma unroll
    for (int q = 0; q < 4; ++q) xc[q] = xp[q][0];

    const int abase = kb * 512 + lane;     // in float4 units within A row
    for (int c = 0; c < 8; ++c) {          // 8 chunks x 256 cols
        if (c < 7) {
#pragma unroll
            for (int q = 0; q < 4; ++q) xn[q] = xp[q][(c + 1) * 64];
        }
#pragma unroll
        for (int r = 0; r < RD; ++r) {
            float4 a4 = A4[(size_t)r * (INCH / 4) + abase + c * 64];
#pragma unroll
            for (int q = 0; q < 4; ++q) {
                acc[q][r] += xc[q].x * a4.x + xc[q].y * a4.y
                           + xc[q].z * a4.z + xc[q].w * a4.w;
            }
        }
        if (c < 7) {
#pragma unroll
            for (int q = 0; q < 4; ++q) xc[q] = xn[q];
        }
    }

    // Cross-lane reduce: LDS transpose (pad 20 -> benign conflicts) + butterfly.
    const int s = lane >> 4, j = lane & 15;
    for (int q = 0; q < 4; ++q) {
#pragma unroll
        for (int k = 0; k < 4; ++k) {
            *reinterpret_cast<float4*>(&scratch[w][lane][k * 4]) =
                make_float4(acc[q][k * 4 + 0], acc[q][k * 4 + 1],
                            acc[q][k * 4 + 2], acc[q][k * 4 + 3]);
        }
        __syncthreads();
        float v = 0.f;
#pragma unroll
        for (int k = 0; k < 16; ++k) v += scratch[w][s * 16 + k][j];
        v += __shfl_xor(v, 16);
        v += __shfl_xor(v, 32);
        if (lane < 16)
            Tp[(size_t)kb * M * RD + (size_t)(row0 + q) * RD + lane] = v;
        __syncthreads();
    }
}

// ---------------------------------------------------------------- kernel 2
// grid = (M/16)*8 blocks of 256 threads. Block = 16 rows x 512 outputs.
// B slice transposed into LDS (conflict-free b128 reads); coalesced f4 stores.
__global__ __launch_bounds__(256, 4)
void lora_tb_kernel(const float* __restrict__ Tp, const float* __restrict__ B,
                    float* __restrict__ OUT, int M) {
    __shared__ float bt[RD][512];          // 32 KB, transposed B slice
    __shared__ float ts[16][RD];           // 1 KB, summed T rows

    const int tid = threadIdx.x;
    const int og  = blockIdx.x & 7;
    const int rg  = blockIdx.x >> 3;
    const int o0  = og * 512;

    // stage B[o0..o0+511][0..15] -> bt[r][o_local]; loads perfectly coalesced
    const float4* B4 = reinterpret_cast<const float4*>(B);
#pragma unroll
    for (int rep = 0; rep < 8; ++rep) {
        int t  = rep * 256 + tid;          // covers 512 o x 4 float4-of-r
        int ol = t >> 2, r4 = t & 3;
        float4 b4 = B4[(size_t)(o0 + ol) * 4 + r4];
        bt[r4 * 4 + 0][ol] = b4.x;
        bt[r4 * 4 + 1][ol] = b4.y;
        bt[r4 * 4 + 2][ol] = b4.z;
        bt[r4 * 4 + 3][ol] = b4.w;
    }
    {
        int row16 = tid >> 4, r = tid & 15;
        int row = rg * 16 + row16;
        ts[row16][r] = Tp[(size_t)row * RD + r]
                     + Tp[(size_t)(M + row) * RD + r];   // sum K-halves
    }
    __syncthreads();

    const int w = tid >> 6, lane = tid & 63;
    const int row0 = rg * 16 + w * 4;

    float4 oa[4], ob[4];
#pragma unroll
    for (int q = 0; q < 4; ++q) {
        oa[q] = make_float4(0.f, 0.f, 0.f, 0.f);
        ob[q] = make_float4(0.f, 0.f, 0.f, 0.f);
    }

#pragma unroll
    for (int r = 0; r < RD; ++r) {
        float4 ba = *reinterpret_cast<const float4*>(&bt[r][lane * 4]);
        float4 bb = *reinterpret_cast<const float4*>(&bt[r][256 + lane * 4]);
#pragma unroll
        for (int q = 0; q < 4; ++q) {
            float t = ts[w * 4 + q][r];    // wave-uniform LDS broadcast
            oa[q].x += t * ba.x; oa[q].y += t * ba.y;
            oa[q].z += t * ba.z; oa[q].w += t * ba.w;
            ob[q].x += t * bb.x; ob[q].y += t * bb.y;
            ob[q].z += t * bb.z; ob[q].w += t * bb.w;
        }
    }

#pragma unroll
    for (int q = 0; q < 4; ++q) {
        size_t base = (size_t)(row0 + q) * OUTCH + o0;
        *reinterpret_cast<float4*>(OUT + base + lane * 4)       = oa[q];
        *reinterpret_cast<float4*>(OUT + base + 256 + lane * 4) = ob[q];
    }
}

extern "C" void kernel_launch(void* const* d_in, const int* in_sizes, int n_in,
                              void* d_out, int out_size, void* d_ws, size_t ws_size,
                              hipStream_t stream) {
    const float* X  = (const float*)d_in[0];   // [M, 4096]
    const float* A  = (const float*)d_in[1];   // [16, 4096]
    const float* Bm = (const float*)d_in[2];   // [4096, 16]
    float*       O  = (float*)d_out;           // [M, 4096]
    float*       Tp = (float*)d_ws;            // [2][M][16] = 1 MB partials

    const int M = in_sizes[0] / INCH;          // 8192

    hipLaunchKernelGGL(lora_xa_kernel, dim3((M / 16) * 2), dim3(256), 0, stream,
                       X, A, Tp, M);
    hipLaunchKernelGGL(lora_tb_kernel, dim3((M / 16) * 8), dim3(256), 0, stream,
                       Tp, Bm, O, M);
}